// Round 1
// baseline (58.824 us; speedup 1.0000x reference)
//
#include <hip/hip_runtime.h>

#define LDIM 4
#define BDIM 32
#define SDIM 512
#define DDIM 768
#define MAX_SPAN 4

// --- kernel 1: mask_len[b] = sum_s masks[b][s] -------------------------------
__global__ void mask_len_kernel(const int* __restrict__ masks,
                                int* __restrict__ mlen) {
    const int b = blockIdx.x;      // one block (64 threads) per batch
    const int lane = threadIdx.x;  // 0..63
    int sum = 0;
    for (int s = lane; s < SDIM; s += 64) sum += masks[b * SDIM + s];
    // 64-lane butterfly reduce
    #pragma unroll
    for (int off = 32; off > 0; off >>= 1) sum += __shfl_xor(sum, off, 64);
    if (lane == 0) mlen[b] = sum;
}

// --- kernel 2: fused mean-over-L + span pool ---------------------------------
// one block per (b,t); 192 threads, each owns one float4 of D (768/4 = 192)
__global__ __launch_bounds__(192)
void span_pool_kernel(const float* __restrict__ hidden,
                      const int* __restrict__ lm_spans,
                      const int* __restrict__ mlen,
                      float* __restrict__ out) {
    const int bt = blockIdx.x;
    const int b  = bt / SDIM;
    const int t  = bt - b * SDIM;
    const int d4 = threadIdx.x;                 // 0..191

    // wave-uniform control values
    const int span_next = (t + 1 < SDIM) ? lm_spans[b * SDIM + t + 1] : 0;
    const bool row_on   = (t < mlen[b] - 2);

    float4 acc = make_float4(0.f, 0.f, 0.f, 0.f);
    if (row_on) {
        const size_t lstride = (size_t)BDIM * SDIM * DDIM;   // L stride in floats
        #pragma unroll
        for (int k = 0; k < MAX_SPAN; ++k) {
            const int idx = t + 1 + k;
            if (k < span_next && idx < SDIM) {
                const float* rowp = hidden + ((size_t)b * SDIM + idx) * DDIM + 4 * d4;
                #pragma unroll
                for (int l = 0; l < LDIM; ++l) {
                    float4 v = *reinterpret_cast<const float4*>(rowp + l * lstride);
                    acc.x += v.x; acc.y += v.y; acc.z += v.z; acc.w += v.w;
                }
            }
        }
        acc.x *= 0.25f; acc.y *= 0.25f; acc.z *= 0.25f; acc.w *= 0.25f;
    }
    reinterpret_cast<float4*>(out + ((size_t)b * SDIM + t) * DDIM)[d4] = acc;
}

extern "C" void kernel_launch(void* const* d_in, const int* in_sizes, int n_in,
                              void* d_out, int out_size, void* d_ws, size_t ws_size,
                              hipStream_t stream) {
    const float* hidden   = (const float*)d_in[0];   // (L,B,S,D) fp32
    const int*   lm_spans = (const int*)d_in[1];     // (B,S) int32
    const int*   masks    = (const int*)d_in[2];     // (B,S) int32
    float*       out      = (float*)d_out;           // (B,S,D) fp32
    int*         mlen     = (int*)d_ws;              // B ints of scratch

    mask_len_kernel<<<BDIM, 64, 0, stream>>>(masks, mlen);
    span_pool_kernel<<<BDIM * SDIM, DDIM / 4, 0, stream>>>(hidden, lm_spans, mlen, out);
}

// Round 2
// 47.681 us; speedup vs baseline: 1.2337x; 1.2337x over previous
//
#include <hip/hip_runtime.h>

#define LDIM 4
#define BDIM 32
#define SDIM 512
#define DDIM 768
#define MAX_SPAN 4
#define TCH 32            // t-rows per block
#define DBLKS 3           // 192 float4 columns / 64 lanes

// --- kernel 1: mask_len[b] = sum_s masks[b][s] -------------------------------
__global__ void mask_len_kernel(const int* __restrict__ masks,
                                int* __restrict__ mlen) {
    const int b = blockIdx.x;
    const int lane = threadIdx.x;
    int sum = 0;
    for (int s = lane; s < SDIM; s += 64) sum += masks[b * SDIM + s];
    #pragma unroll
    for (int off = 32; off > 0; off >>= 1) sum += __shfl_xor(sum, off, 64);
    if (lane == 0) mlen[b] = sum;
}

// --- kernel 2: streaming mean-over-L + span pool -----------------------------
// block = 1 wave (64 threads). blockIdx.x = ((b*CHUNKS + chunk)*DBLKS + dblk).
// Each thread owns one float4 column; rows are read exactly once and pushed
// through a 4-deep register ring of pending outputs.
__global__ __launch_bounds__(64)
void span_pool_stream_kernel(const float* __restrict__ hidden,
                             const int* __restrict__ lm_spans,
                             const int* __restrict__ mlen,
                             float* __restrict__ out) {
    const int CHUNKS = SDIM / TCH;
    int id = blockIdx.x;
    const int dblk = id % DBLKS;  id /= DBLKS;
    const int chunk = id % CHUNKS;
    const int b = id / CHUNKS;

    const int t0 = chunk * TCH;                       // t0 % 4 == 0
    const int d4 = dblk * 64 + threadIdx.x;           // float4 column 0..191
    const int ml2 = mlen[b] - 2;

    const size_t lstride = (size_t)BDIM * SDIM * DDIM;
    const float* base = hidden + (size_t)b * SDIM * DDIM + 4 * d4;
    float* outb = out + (size_t)b * SDIM * DDIM + 4 * d4;
    const int* spanb = lm_spans + b * SDIM;

    float4 acc[4];
    int spn[4];
    bool on[4];
    #pragma unroll
    for (int u = 0; u < 4; ++u) {
        acc[u] = make_float4(0.f, 0.f, 0.f, 0.f);
        spn[u] = 0;
        on[u] = false;
    }

    for (int tb = t0; tb < t0 + TCH + 8; tb += 4) {
        #pragma unroll
        for (int u = 0; u < 4; ++u) {
            const int t = tb + u;                     // row index; t & 3 == u

            // 1. load row t slice (sum of L layers); zero if out of range
            float4 m = make_float4(0.f, 0.f, 0.f, 0.f);
            if (t >= t0 + 1 && t <= t0 + TCH + 3 && t < SDIM) {
                const float* rp = base + (size_t)t * DDIM;
                #pragma unroll
                for (int l = 0; l < LDIM; ++l) {
                    float4 v = *reinterpret_cast<const float4*>(rp + l * lstride);
                    m.x += v.x; m.y += v.y; m.z += v.z; m.w += v.w;
                }
            }

            // 2. accumulate row t into pending outputs t-1..t-4 (static slots)
            #pragma unroll
            for (int j = 1; j <= 4; ++j) {
                const int s = (u - j) & 3;
                if (j <= spn[s]) {                    // wave-uniform
                    acc[s].x += m.x; acc[s].y += m.y;
                    acc[s].z += m.z; acc[s].w += m.w;
                }
            }

            // 3. finalize slot u (output t' = t-4)
            const int tp = t - 4;
            if (tp >= t0 && tp < t0 + TCH) {
                float4 o = make_float4(0.f, 0.f, 0.f, 0.f);
                if (on[u]) {
                    o.x = acc[u].x * 0.25f; o.y = acc[u].y * 0.25f;
                    o.z = acc[u].z * 0.25f; o.w = acc[u].w * 0.25f;
                }
                *reinterpret_cast<float4*>(outb + (size_t)tp * DDIM) = o;
            }

            // 4. re-init slot u for output t' = t
            if (t < t0 + TCH) {
                acc[u] = make_float4(0.f, 0.f, 0.f, 0.f);
                spn[u] = (t + 1 < SDIM) ? spanb[t + 1] : 0;
                on[u]  = (t < ml2);
            } else {
                spn[u] = 0;
                on[u] = false;
            }
        }
    }
}

extern "C" void kernel_launch(void* const* d_in, const int* in_sizes, int n_in,
                              void* d_out, int out_size, void* d_ws, size_t ws_size,
                              hipStream_t stream) {
    const float* hidden   = (const float*)d_in[0];   // (L,B,S,D) fp32
    const int*   lm_spans = (const int*)d_in[1];     // (B,S) int32
    const int*   masks    = (const int*)d_in[2];     // (B,S) int32
    float*       out      = (float*)d_out;           // (B,S,D) fp32
    int*         mlen     = (int*)d_ws;              // B ints of scratch

    mask_len_kernel<<<BDIM, 64, 0, stream>>>(masks, mlen);
    const int CHUNKS = SDIM / TCH;
    span_pool_stream_kernel<<<BDIM * CHUNKS * DBLKS, 64, 0, stream>>>(
        hidden, lm_spans, mlen, out);
}

// Round 3
// 39.839 us; speedup vs baseline: 1.4765x; 1.1968x over previous
//
#include <hip/hip_runtime.h>

#define LDIM 4
#define BDIM 32
#define SDIM 512
#define DDIM 768
#define MAX_SPAN 4
#define TCH 32            // t-rows per block
#define DBLKS 3           // 192 float4 columns / 64 lanes

// Fused kernel: per-block mask_len reduce + streaming mean-over-L + span pool.
// block = 1 wave (64 threads). blockIdx.x = ((b*CHUNKS + chunk)*DBLKS + dblk).
// Each thread owns one float4 column; rows are read exactly once (and skipped
// entirely when no pending output needs them) and pushed through a 4-deep
// register ring of pending outputs.
__global__ __launch_bounds__(64)
void span_pool_stream_kernel(const float* __restrict__ hidden,
                             const int* __restrict__ lm_spans,
                             const int* __restrict__ masks,
                             float* __restrict__ out) {
    const int CHUNKS = SDIM / TCH;
    int id = blockIdx.x;
    const int dblk = id % DBLKS;  id /= DBLKS;
    const int chunk = id % CHUNKS;
    const int b = id / CHUNKS;

    const int t0 = chunk * TCH;                       // t0 % 4 == 0
    const int lane = threadIdx.x;
    const int d4 = dblk * 64 + lane;                  // float4 column 0..191

    // --- fused mask_len[b] (masks are L2-resident; 8 loads + butterfly) ---
    int msum = 0;
    #pragma unroll
    for (int i = 0; i < SDIM / 64; ++i) msum += masks[b * SDIM + i * 64 + lane];
    #pragma unroll
    for (int off = 32; off > 0; off >>= 1) msum += __shfl_xor(msum, off, 64);
    const int ml2 = msum - 2;

    const size_t lstride = (size_t)BDIM * SDIM * DDIM;
    const float* base = hidden + (size_t)b * SDIM * DDIM + 4 * d4;
    float* outb = out + (size_t)b * SDIM * DDIM + 4 * d4;
    const int* spanb = lm_spans + b * SDIM;

    float4 acc[4];
    int spn[4];
    bool on[4];
    #pragma unroll
    for (int u = 0; u < 4; ++u) {
        acc[u] = make_float4(0.f, 0.f, 0.f, 0.f);
        spn[u] = 0;
        on[u] = false;
    }

    for (int tb = t0; tb < t0 + TCH + 4; tb += 4) {
        #pragma unroll
        for (int u = 0; u < 4; ++u) {
            const int t = tb + u;                     // row index; t & 3 == u

            // dead-row test: does ANY pending output need row t? (wave-uniform)
            const bool need = (spn[(u - 1) & 3] >= 1) | (spn[(u - 2) & 3] >= 2) |
                              (spn[(u - 3) & 3] >= 3) | (spn[u] >= 4);

            // 1. load row t slice (sum of L layers); zero if out of range/dead
            float4 m = make_float4(0.f, 0.f, 0.f, 0.f);
            if (need && t >= t0 + 1 && t <= t0 + TCH + 3 && t < SDIM) {
                const float* rp = base + (size_t)t * DDIM;
                #pragma unroll
                for (int l = 0; l < LDIM; ++l) {
                    float4 v = *reinterpret_cast<const float4*>(rp + l * lstride);
                    m.x += v.x; m.y += v.y; m.z += v.z; m.w += v.w;
                }
            }

            // 2. accumulate row t into pending outputs t-1..t-4 (static slots)
            #pragma unroll
            for (int j = 1; j <= 4; ++j) {
                const int s = (u - j) & 3;
                if (j <= spn[s]) {                    // wave-uniform
                    acc[s].x += m.x; acc[s].y += m.y;
                    acc[s].z += m.z; acc[s].w += m.w;
                }
            }

            // 3. finalize slot u (output t' = t-4)
            const int tp = t - 4;
            if (tp >= t0 && tp < t0 + TCH) {
                float4 o = make_float4(0.f, 0.f, 0.f, 0.f);
                if (on[u]) {
                    o.x = acc[u].x * 0.25f; o.y = acc[u].y * 0.25f;
                    o.z = acc[u].z * 0.25f; o.w = acc[u].w * 0.25f;
                }
                *reinterpret_cast<float4*>(outb + (size_t)tp * DDIM) = o;
            }

            // 4. re-init slot u for output t' = t
            if (t < t0 + TCH) {
                acc[u] = make_float4(0.f, 0.f, 0.f, 0.f);
                spn[u] = (t + 1 < SDIM) ? spanb[t + 1] : 0;
                on[u]  = (t < ml2);
            } else {
                spn[u] = 0;
                on[u] = false;
            }
        }
    }
}

extern "C" void kernel_launch(void* const* d_in, const int* in_sizes, int n_in,
                              void* d_out, int out_size, void* d_ws, size_t ws_size,
                              hipStream_t stream) {
    const float* hidden   = (const float*)d_in[0];   // (L,B,S,D) fp32
    const int*   lm_spans = (const int*)d_in[1];     // (B,S) int32
    const int*   masks    = (const int*)d_in[2];     // (B,S) int32
    float*       out      = (float*)d_out;           // (B,S,D) fp32

    const int CHUNKS = SDIM / TCH;
    span_pool_stream_kernel<<<BDIM * CHUNKS * DBLKS, 64, 0, stream>>>(
        hidden, lm_spans, masks, out);
}

// Round 4
// 39.603 us; speedup vs baseline: 1.4853x; 1.0060x over previous
//
#include <hip/hip_runtime.h>

#define LDIM 4
#define BDIM 32
#define SDIM 512
#define DDIM 768
#define MAX_SPAN 4
#define TCH 32            // t-rows per block
#define DBLKS 3           // 192 float4 columns / 64 lanes

typedef float v4f __attribute__((ext_vector_type(4)));

// Fused kernel: per-block mask_len reduce + streaming mean-over-L + span pool.
// block = 1 wave (64 threads). blockIdx.x = ((b*CHUNKS + chunk)*DBLKS + dblk).
// Each thread owns one float4 column; rows are read exactly once (and skipped
// entirely when no pending output needs them) and pushed through a 4-deep
// register ring of pending outputs. Output stores are non-temporal so the
// 48 MB of write-once data doesn't evict the (L3-resident) 192 MB input.
__global__ __launch_bounds__(64)
void span_pool_stream_kernel(const float* __restrict__ hidden,
                             const int* __restrict__ lm_spans,
                             const int* __restrict__ masks,
                             float* __restrict__ out) {
    const int CHUNKS = SDIM / TCH;
    int id = blockIdx.x;
    const int dblk = id % DBLKS;  id /= DBLKS;
    const int chunk = id % CHUNKS;
    const int b = id / CHUNKS;

    const int t0 = chunk * TCH;                       // t0 % 4 == 0
    const int lane = threadIdx.x;
    const int d4 = dblk * 64 + lane;                  // float4 column 0..191

    // --- fused mask_len[b] (masks are L2-resident; 8 loads + butterfly) ---
    int msum = 0;
    #pragma unroll
    for (int i = 0; i < SDIM / 64; ++i) msum += masks[b * SDIM + i * 64 + lane];
    #pragma unroll
    for (int off = 32; off > 0; off >>= 1) msum += __shfl_xor(msum, off, 64);
    const int ml2 = msum - 2;

    const size_t lstride = (size_t)BDIM * SDIM * DDIM;
    const float* base = hidden + (size_t)b * SDIM * DDIM + 4 * d4;
    float* outb = out + (size_t)b * SDIM * DDIM + 4 * d4;
    const int* spanb = lm_spans + b * SDIM;

    float4 acc[4];
    int spn[4];
    bool on[4];
    #pragma unroll
    for (int u = 0; u < 4; ++u) {
        acc[u] = make_float4(0.f, 0.f, 0.f, 0.f);
        spn[u] = 0;
        on[u] = false;
    }

    for (int tb = t0; tb < t0 + TCH + 4; tb += 4) {
        #pragma unroll
        for (int u = 0; u < 4; ++u) {
            const int t = tb + u;                     // row index; t & 3 == u

            // dead-row test: does ANY pending output need row t? (wave-uniform)
            const bool need = (spn[(u - 1) & 3] >= 1) | (spn[(u - 2) & 3] >= 2) |
                              (spn[(u - 3) & 3] >= 3) | (spn[u] >= 4);

            // 1. load row t slice (sum of L layers); zero if out of range/dead
            float4 m = make_float4(0.f, 0.f, 0.f, 0.f);
            if (need && t >= t0 + 1 && t <= t0 + TCH + 3 && t < SDIM) {
                const float* rp = base + (size_t)t * DDIM;
                #pragma unroll
                for (int l = 0; l < LDIM; ++l) {
                    float4 v = *reinterpret_cast<const float4*>(rp + l * lstride);
                    m.x += v.x; m.y += v.y; m.z += v.z; m.w += v.w;
                }
            }

            // 2. accumulate row t into pending outputs t-1..t-4 (static slots)
            #pragma unroll
            for (int j = 1; j <= 4; ++j) {
                const int s = (u - j) & 3;
                if (j <= spn[s]) {                    // wave-uniform
                    acc[s].x += m.x; acc[s].y += m.y;
                    acc[s].z += m.z; acc[s].w += m.w;
                }
            }

            // 3. finalize slot u (output t' = t-4); non-temporal store
            const int tp = t - 4;
            if (tp >= t0 && tp < t0 + TCH) {
                v4f o = (v4f)(0.f);
                if (on[u]) {
                    o.x = acc[u].x * 0.25f; o.y = acc[u].y * 0.25f;
                    o.z = acc[u].z * 0.25f; o.w = acc[u].w * 0.25f;
                }
                __builtin_nontemporal_store(
                    o, reinterpret_cast<v4f*>(outb + (size_t)tp * DDIM));
            }

            // 4. re-init slot u for output t' = t
            if (t < t0 + TCH) {
                acc[u] = make_float4(0.f, 0.f, 0.f, 0.f);
                spn[u] = (t + 1 < SDIM) ? spanb[t + 1] : 0;
                on[u]  = (t < ml2);
            } else {
                spn[u] = 0;
                on[u] = false;
            }
        }
    }
}

extern "C" void kernel_launch(void* const* d_in, const int* in_sizes, int n_in,
                              void* d_out, int out_size, void* d_ws, size_t ws_size,
                              hipStream_t stream) {
    const float* hidden   = (const float*)d_in[0];   // (L,B,S,D) fp32
    const int*   lm_spans = (const int*)d_in[1];     // (B,S) int32
    const int*   masks    = (const int*)d_in[2];     // (B,S) int32
    float*       out      = (float*)d_out;           // (B,S,D) fp32

    const int CHUNKS = SDIM / TCH;
    span_pool_stream_kernel<<<BDIM * CHUNKS * DBLKS, 64, 0, stream>>>(
        hidden, lm_spans, masks, out);
}